// Round 7
// baseline (153.681 us; speedup 1.0000x reference)
//
#include <hip/hip_runtime.h>
#include <hip/hip_bf16.h>

#define NB 4
#define NC 128
#define NH 128
#define NW 240
#define NE 64
#define NK 9
#define PLANE (NH*NW)        // 30720: stride between channels
#define CHW (NC*PLANE)

typedef __attribute__((ext_vector_type(8))) short short8;
typedef __attribute__((ext_vector_type(4))) float f32x4;
typedef __attribute__((ext_vector_type(2))) __fp16 fp16x2;
typedef __attribute__((ext_vector_type(8))) __fp16 fp16x8;

__device__ __forceinline__ unsigned pkh(float x, float y){
  fp16x2 h = __builtin_amdgcn_cvt_pkrtz(x, y);
  return __builtin_bit_cast(unsigned, h);
}
__device__ __forceinline__ float fdot2u(unsigned a, unsigned b, float c){
#if __has_builtin(__builtin_amdgcn_fdot2)
  return __builtin_amdgcn_fdot2(__builtin_bit_cast(fp16x2,a),
                                __builtin_bit_cast(fp16x2,b), c, false);
#else
  fp16x2 ha = __builtin_bit_cast(fp16x2,a), hb = __builtin_bit_cast(fp16x2,b);
  return c + (float)ha[0]*(float)hb[0] + (float)ha[1]*(float)hb[1];
#endif
}
__device__ __forceinline__ int swz(int r){ return (r ^ (r>>3)) & 7; }

// async global->LDS, 16 B per lane. g: per-lane global addr (16B aligned);
// lds_u: wave-uniform LDS base; HW adds lane*16.
__device__ __forceinline__ void gload_lds16(const float* g, float* lds_u, int lane){
#if __has_builtin(__builtin_amdgcn_global_load_lds)
  __builtin_amdgcn_global_load_lds(
      (const __attribute__((address_space(1))) unsigned*)g,
      (__attribute__((address_space(3))) unsigned*)lds_u, 16, 0, 0);
#else
  *(float4*)(lds_u + 4*lane) = *(const float4*)g;   // sync fallback
#endif
}

// Counted-vmcnt barrier: NO full drain in the main loop (T4).
// lgkmcnt(0) makes prior ds_writes (phi staging) visible across the barrier.
// sched_barrier(0) stops hipcc hoisting LDS-dependent ops above it (rule #18).
#define WAITB(N) do {                                                        \
    asm volatile("s_waitcnt vmcnt(" #N ") lgkmcnt(0)" ::: "memory");         \
    __builtin_amdgcn_s_barrier();                                            \
    __builtin_amdgcn_sched_barrier(0);                                       \
  } while (0)

// ======================================================================
// Fused kernel, deep-pipelined DMA staging. One block per (b,h) row.
// 512 blocks x 1024 thr. LDS: 4 x 30,720 B fp32 chunk bufs + phis fp16
// 17,408 B = 140,288 B -> 1 blk/CU (R4/R5 showed 1 vs 2 blk/CU is neutral).
// Pipeline: prologue issues chunks 0..2; round k: counted-wait (chunk k
// done, k+1..k+2 still flying) -> raw s_barrier -> issue chunk k+3 ->
// MFMA on chunk k. Own-wave 3 chunks (6 KB) in flight across barriers.
// ======================================================================
__global__ __launch_bounds__(1024, 4)
void fused_kernel(const float* __restrict__ xL,
                  const float* __restrict__ xR,
                  const float* __restrict__ d0g,
                  const float* __restrict__ phig,
                  float* __restrict__ outg)
{
  __shared__ __attribute__((aligned(16))) float bufs[4*7680];           // 122,880 B
  __shared__ __attribute__((aligned(16))) unsigned short phis[NE*136];  // 17,408 B

  const int tid  = threadIdx.x;
  const int lane = tid & 63;
  const int wv   = tid >> 6;
  const int b    = blockIdx.x >> 7;
  const int h    = blockIdx.x & 127;
  const size_t base = (size_t)b*CHW + (size_t)h*NW;
  const int pixbase = (b*NH + h)*NW;

  const int mrow = lane & 15;
  const int kg   = lane >> 4;
  const int nt   = wv;                 // 16 waves, nt<15 active
  const int n    = 16*nt + mrow;       // owned pixel column

  // chunk q (0..7): side = q<4 ? L : R, channels 32*(q&3), buffer q&3.
  // 32ch x 60 f4 = 1920 f4 = 30 wave-insts; wave w issues qq = 2w, 2w+1.
  auto issue_chunk = [&](int q){
    const float* src = (q < 4) ? xL : xR;
    const int cb = 32*(q & 3);
    float* buf = &bufs[(q & 3)*7680];
    #pragma unroll
    for (int i = 0; i < 2; ++i) {
      int qq = 2*wv + i;
      if (qq < 30) {
        int g4 = qq*64 + lane;
        int c = g4/60, s4 = g4 - 60*c;
        gload_lds16(src + base + (size_t)(cb + c)*PLANE + 4*s4,
                    buf + qq*256, lane);
      }
    }
  };

  auto gemm_round = [&](const float* bf, int cb, f32x4 (&acc)[4]){
    if (nt < 15) {
      fp16x8 bv;
      #pragma unroll
      for (int j = 0; j < 8; ++j)
        bv[j] = (__fp16)bf[(8*kg + j)*240 + n];
      #pragma unroll
      for (int mt = 0; mt < 4; ++mt) {
        short8 raw = *(const short8*)&phis[(16*mt + mrow)*136 + cb + 8*kg];
        fp16x8 af = __builtin_bit_cast(fp16x8, raw);
        acc[mt] = __builtin_amdgcn_mfma_f32_16x16x32_f16(af, bv, acc[mt], 0, 0, 0);
      }
    }
  };

  auto norm_pack = [&](f32x4 (&acc)[4], uint2 (&pk)[4]){
    float ss = 0.f;
    #pragma unroll
    for (int mt = 0; mt < 4; ++mt)
      #pragma unroll
      for (int r = 0; r < 4; ++r)
        ss += acc[mt][r]*acc[mt][r];
    ss += __shfl_xor(ss, 16, 64);
    ss += __shfl_xor(ss, 32, 64);
    float inv = 1.f/(sqrtf(ss) + 1e-6f);
    #pragma unroll
    for (int mt = 0; mt < 4; ++mt) {
      pk[mt].x = pkh(acc[mt][0]*inv, acc[mt][1]*inv);
      pk[mt].y = pkh(acc[mt][2]*inv, acc[mt][3]*inv);
    }
  };

  auto frag_write = [&](unsigned short* dst, uint2 (&pk)[4]){
    #pragma unroll
    for (int mt = 0; mt < 4; ++mt) {
      int e0 = 16*mt + 4*kg;
      int pos = n*64 + (((e0>>3) ^ swz(n))<<3) + (e0&7);
      *(uint2*)&dst[pos] = pk[mt];
    }
  };

  // ---- prologue: scalar loads first (oldest -> retire first), then
  //      issue chunks 0..2, then convert phi into LDS ----
  float d0v = (tid < 960) ? d0g[pixbase + (tid >> 2)] : 0.f;
  float4 pr[2];
  #pragma unroll
  for (int i = 0; i < 2; ++i) {
    int idx = i*1024 + tid;
    pr[i] = *(const float4*)(phig + (idx>>5)*128 + 4*(idx&31));
  }
  issue_chunk(0);
  issue_chunk(1);
  issue_chunk(2);
  #pragma unroll
  for (int i = 0; i < 2; ++i) {
    int idx = i*1024 + tid;
    uint2 pk; pk.x = pkh(pr[i].x, pr[i].y); pk.y = pkh(pr[i].z, pr[i].w);
    *(uint2*)&phis[(idx>>5)*136 + 4*(idx&31)] = pk;
  }

  f32x4 accL[4], accR[4];
  #pragma unroll
  for (int mt = 0; mt < 4; ++mt) {
    accL[mt] = (f32x4){0.f,0.f,0.f,0.f};
    accR[mt] = (f32x4){0.f,0.f,0.f,0.f};
  }
  uint2 flpk[4], frpk[4];

  // ---- 8 rounds, counted-vmcnt pipeline (N = 2 x #newer chunks) ----
  WAITB(4); issue_chunk(3); gemm_round(&bufs[0*7680],  0, accL);
  WAITB(4); issue_chunk(4); gemm_round(&bufs[1*7680], 32, accL);
  WAITB(4); issue_chunk(5); gemm_round(&bufs[2*7680], 64, accL);
  WAITB(4); issue_chunk(6); gemm_round(&bufs[3*7680], 96, accL);
  if (nt < 15) norm_pack(accL, flpk);
  WAITB(4); issue_chunk(7); gemm_round(&bufs[0*7680],  0, accR);
  WAITB(4);                 gemm_round(&bufs[1*7680], 32, accR);
  WAITB(2);                 gemm_round(&bufs[2*7680], 64, accR);
  WAITB(0);                 gemm_round(&bufs[3*7680], 96, accR);
  if (nt < 15) norm_pack(accR, frpk);

  // ---- epilogue: frags -> swizzled pixel-major LDS (bufs 0/1 free) ----
  unsigned short* FLb = (unsigned short*)&bufs[0*7680];  // 240x64 fp16
  unsigned short* FRb = (unsigned short*)&bufs[1*7680];
  if (nt < 15) {
    frag_write(FLb, flpk);
    frag_write(FRb, frpk);
  }
  __syncthreads();

  // ---- cost (p = tid>>2, 4-way e-split, fdot2) ----
  float* cvb = (float*)phis;           // 8,640 B <= 17,408; phis reads done
  if (tid < 960) {
    const int p  = tid >> 2;
    const int eh = tid & 3;
    float xf  = (float)p - d0v;
    float x0  = floorf(xf);
    float wfr = xf - x0;
    int jb = (int)x0 - 4;

    unsigned fl[8];
    #pragma unroll
    for (int i = 0; i < 2; ++i) {
      int c4 = 2*eh + i;
      uint4 raw = *(const uint4*)&FLb[p*64 + ((c4 ^ swz(p))<<3)];
      fl[4*i+0]=raw.x; fl[4*i+1]=raw.y; fl[4*i+2]=raw.z; fl[4*i+3]=raw.w;
    }

    float D[10];
    #pragma unroll
    for (int t = 0; t < 10; ++t) {
      int j = jb + t;
      j = j < 0 ? 0 : (j > NW-1 ? NW-1 : j);
      float s = 0.f;
      #pragma unroll
      for (int i = 0; i < 2; ++i) {
        int c4 = 2*eh + i;
        uint4 raw = *(const uint4*)&FRb[j*64 + ((c4 ^ swz(j))<<3)];
        s = fdot2u(fl[4*i+0], raw.x, s);
        s = fdot2u(fl[4*i+1], raw.y, s);
        s = fdot2u(fl[4*i+2], raw.z, s);
        s = fdot2u(fl[4*i+3], raw.w, s);
      }
      D[t] = s;
    }
    #pragma unroll
    for (int t = 0; t < 10; ++t) {
      D[t] += __shfl_xor(D[t], 1, 64);
      D[t] += __shfl_xor(D[t], 2, 64);
    }

    #define WK(k) { const int t0 = 8-(k); cvb[(k)*NW + p] = (1.f - wfr)*D[t0] + wfr*D[t0+1]; }
    if      (eh == 0) { WK(0) WK(1) WK(2) }
    else if (eh == 1) { WK(3) WK(4) }
    else if (eh == 2) { WK(5) WK(6) }
    else              { WK(7) WK(8) }
    #undef WK
  }
  __syncthreads();

  // ---- coalesced out store: 540 float4 (9 k-planes x 60) ----
  if (tid < 540) {
    int k = tid/60, w4 = tid - 60*k;
    float4 v = *(const float4*)&cvb[k*NW + 4*w4];
    *(float4*)(outg + (size_t)b*NK*PLANE + (size_t)h*NW + (size_t)k*PLANE + 4*w4) = v;
  }
}

extern "C" void kernel_launch(void* const* d_in, const int* in_sizes, int n_in,
                              void* d_out, int out_size, void* d_ws, size_t ws_size,
                              hipStream_t stream) {
  const float* xL   = (const float*)d_in[0];
  const float* xR   = (const float*)d_in[1];
  const float* d0g  = (const float*)d_in[2];
  const float* phig = (const float*)d_in[3];
  float* outg = (float*)d_out;
  fused_kernel<<<dim3(NB*NH), dim3(1024), 0, stream>>>(xL, xR, d0g, phig, outg);
}

// Round 8
// 152.717 us; speedup vs baseline: 1.0063x; 1.0063x over previous
//
#include <hip/hip_runtime.h>
#include <hip/hip_bf16.h>

#define NB 4
#define NC 128
#define NH 128
#define NW 240
#define NE 64
#define NK 9
#define PLANE (NH*NW)        // 30720
#define CHW (NC*PLANE)
#define P2 480               // pixels per block (2 rows)

typedef __attribute__((ext_vector_type(8))) short short8;
typedef __attribute__((ext_vector_type(4))) float f32x4;
typedef __attribute__((ext_vector_type(2))) __fp16 fp16x2;
typedef __attribute__((ext_vector_type(8))) __fp16 fp16x8;

__device__ __forceinline__ unsigned pkh(float x, float y){
  fp16x2 h = __builtin_amdgcn_cvt_pkrtz(x, y);
  return __builtin_bit_cast(unsigned, h);
}
__device__ __forceinline__ float fdot2u(unsigned a, unsigned b, float c){
#if __has_builtin(__builtin_amdgcn_fdot2)
  return __builtin_amdgcn_fdot2(__builtin_bit_cast(fp16x2,a),
                                __builtin_bit_cast(fp16x2,b), c, false);
#else
  fp16x2 ha = __builtin_bit_cast(fp16x2,a), hb = __builtin_bit_cast(fp16x2,b);
  return c + (float)ha[0]*(float)hb[0] + (float)ha[1]*(float)hb[1];
#endif
}
__device__ __forceinline__ int swz(int r){ return (r ^ (r>>3)) & 7; }

__device__ __forceinline__ void gload_lds16(const float* g, float* lds_u, int lane){
#if __has_builtin(__builtin_amdgcn_global_load_lds)
  __builtin_amdgcn_global_load_lds(
      (const __attribute__((address_space(1))) unsigned*)g,
      (__attribute__((address_space(3))) unsigned*)lds_u, 16, 0, 0);
#else
  *(float4*)(lds_u + 4*lane) = *(const float4*)g;
#endif
}

#define WAITB(N) do {                                                        \
    asm volatile("s_waitcnt vmcnt(" #N ") lgkmcnt(0)" ::: "memory");         \
    __builtin_amdgcn_s_barrier();                                            \
    __builtin_amdgcn_sched_barrier(0);                                       \
  } while (0)

// ======================================================================
// 2-row blocks: grid 256 = 1 block/CU (single generation). 1024 thr.
// Chunk = 16 ch x 480 px fp32 = 30,720 B, contiguous 1920-B segments.
// 16 chunks (L0..7, R0..7), 4 bufs, counted-vmcnt 3-deep pipeline.
// GEMM: 16x16x32_f16 MFMA with upper K half zeroed (exact).
// LDS: 4x30,720 + phis 17,408 = 140,288 B. FLb=bufs0-1, FRb=bufs2-3,
// cvb aliases phis.
// ======================================================================
__global__ __launch_bounds__(1024, 4)
void fused_kernel(const float* __restrict__ xL,
                  const float* __restrict__ xR,
                  const float* __restrict__ d0g,
                  const float* __restrict__ phig,
                  float* __restrict__ outg)
{
  __shared__ __attribute__((aligned(16))) float bufs[4*7680];           // 122,880 B
  __shared__ __attribute__((aligned(16))) unsigned short phis[NE*136];  // 17,408 B

  const int tid  = threadIdx.x;
  const int lane = tid & 63;
  const int wv   = tid >> 6;
  const int b    = blockIdx.x >> 6;    // 256 blocks: b, h-pair
  const int hp   = blockIdx.x & 63;
  const size_t base = (size_t)b*CHW + (size_t)hp*P2;   // x[b][0][2hp][0]
  const int pixbase = b*PLANE + hp*P2;                  // d0/out pixel base

  const int mrow = lane & 15;
  const int kg   = lane >> 4;

  // chunk q in [0,16): side q>>3, kq=q&7 -> 16 channels, buf q&3.
  // 1920 float4 per chunk = 30 wave-instrs; waves 0..14 issue 2 each.
  auto issue_chunk = [&](int q){
    const float* src = (q < 8) ? xL : xR;
    const int kq = q & 7;
    float* buf = &bufs[(q & 3)*7680];
    #pragma unroll
    for (int i = 0; i < 2; ++i) {
      int qq = 2*wv + i;
      if (qq < 30) {
        int g4 = qq*64 + lane;
        int c = g4/120, s4 = g4 - 120*c;     // [16 ch][120 f4]
        gload_lds16(src + base + (size_t)(16*kq + c)*PLANE + 4*s4,
                    buf + qq*256, lane);
      }
    }
  };

  // one K=16 slice over 480 pixels; wave w<15 owns n-tiles {w, w+15}
  auto gemm_round = [&](int q, f32x4 (&acc)[2][4]){
    const int kq = q & 7;
    const float* bf = &bufs[(q & 3)*7680];
    if (wv < 15) {
      short8 rawA[4];
      #pragma unroll
      for (int mt = 0; mt < 4; ++mt) rawA[mt] = (short8){0,0,0,0,0,0,0,0};
      if (kg < 2) {
        #pragma unroll
        for (int mt = 0; mt < 4; ++mt)
          rawA[mt] = *(const short8*)&phis[(16*mt + mrow)*136 + 16*kq + 8*kg];
      }
      #pragma unroll
      for (int tt = 0; tt < 2; ++tt) {
        const int n = 16*(wv + 15*tt) + mrow;
        fp16x8 bv;
        #pragma unroll
        for (int j = 0; j < 8; ++j) bv[j] = (__fp16)0.f;
        if (kg < 2) {
          #pragma unroll
          for (int j = 0; j < 8; ++j)
            bv[j] = (__fp16)bf[(8*kg + j)*P2 + n];
        }
        #pragma unroll
        for (int mt = 0; mt < 4; ++mt) {
          fp16x8 af = __builtin_bit_cast(fp16x8, rawA[mt]);
          acc[tt][mt] = __builtin_amdgcn_mfma_f32_16x16x32_f16(af, bv, acc[tt][mt], 0, 0, 0);
        }
      }
    }
  };

  auto norm_pack = [&](f32x4 (&acc)[2][4], uint2 (&pk)[2][4]){
    #pragma unroll
    for (int tt = 0; tt < 2; ++tt) {
      float ss = 0.f;
      #pragma unroll
      for (int mt = 0; mt < 4; ++mt)
        #pragma unroll
        for (int r = 0; r < 4; ++r)
          ss += acc[tt][mt][r]*acc[tt][mt][r];
      ss += __shfl_xor(ss, 16, 64);
      ss += __shfl_xor(ss, 32, 64);
      float inv = 1.f/(sqrtf(ss) + 1e-6f);
      #pragma unroll
      for (int mt = 0; mt < 4; ++mt) {
        pk[tt][mt].x = pkh(acc[tt][mt][0]*inv, acc[tt][mt][1]*inv);
        pk[tt][mt].y = pkh(acc[tt][mt][2]*inv, acc[tt][mt][3]*inv);
      }
    }
  };

  auto frag_write = [&](unsigned short* dst, uint2 (&pk)[2][4]){
    #pragma unroll
    for (int tt = 0; tt < 2; ++tt) {
      const int n = 16*(wv + 15*tt) + mrow;
      #pragma unroll
      for (int mt = 0; mt < 4; ++mt) {
        int e0 = 16*mt + 4*kg;
        int pos = n*64 + (((e0>>3) ^ swz(n))<<3) + (e0&7);
        *(uint2*)&dst[pos] = pk[tt][mt];
      }
    }
  };

  // ---- prologue: d0 + phi (loads drained by phi ds_write), then c0..c2 ----
  float d0v = (tid < 960) ? d0g[pixbase + (tid >> 1)] : 0.f;
  float4 pr[2];
  #pragma unroll
  for (int i = 0; i < 2; ++i) {
    int idx = i*1024 + tid;
    pr[i] = *(const float4*)(phig + (idx>>5)*128 + 4*(idx&31));
  }
  #pragma unroll
  for (int i = 0; i < 2; ++i) {
    int idx = i*1024 + tid;
    uint2 pk; pk.x = pkh(pr[i].x, pr[i].y); pk.y = pkh(pr[i].z, pr[i].w);
    *(uint2*)&phis[(idx>>5)*136 + 4*(idx&31)] = pk;
  }
  issue_chunk(0); issue_chunk(1); issue_chunk(2);

  f32x4 accL[2][4], accR[2][4];
  #pragma unroll
  for (int tt = 0; tt < 2; ++tt)
    #pragma unroll
    for (int mt = 0; mt < 4; ++mt) {
      accL[tt][mt] = (f32x4){0.f,0.f,0.f,0.f};
      accR[tt][mt] = (f32x4){0.f,0.f,0.f,0.f};
    }
  uint2 flpk[2][4], frpk[2][4];

  // ---- 16 rounds, 3-deep counted-vmcnt ----
  WAITB(4); issue_chunk(3);  gemm_round(0,  accL);
  WAITB(4); issue_chunk(4);  gemm_round(1,  accL);
  WAITB(4); issue_chunk(5);  gemm_round(2,  accL);
  WAITB(4); issue_chunk(6);  gemm_round(3,  accL);
  WAITB(4); issue_chunk(7);  gemm_round(4,  accL);
  WAITB(4); issue_chunk(8);  gemm_round(5,  accL);
  WAITB(4); issue_chunk(9);  gemm_round(6,  accL);
  WAITB(4); issue_chunk(10); gemm_round(7,  accL);
  if (wv < 15) norm_pack(accL, flpk);
  WAITB(4); issue_chunk(11); gemm_round(8,  accR);
  WAITB(4); issue_chunk(12); gemm_round(9,  accR);
  WAITB(4); issue_chunk(13); gemm_round(10, accR);
  WAITB(4); issue_chunk(14); gemm_round(11, accR);
  WAITB(4); issue_chunk(15); gemm_round(12, accR);
  WAITB(4);                  gemm_round(13, accR);
  WAITB(2);                  gemm_round(14, accR);
  WAITB(0);                  gemm_round(15, accR);
  if (wv < 15) norm_pack(accR, frpk);

  // ---- epilogue: all buf reads done -> overwrite with FL/FR frags ----
  asm volatile("s_waitcnt lgkmcnt(0)" ::: "memory");
  __builtin_amdgcn_s_barrier();
  __builtin_amdgcn_sched_barrier(0);
  unsigned short* FLb = (unsigned short*)&bufs[0];        // 480x64 fp16
  unsigned short* FRb = (unsigned short*)&bufs[2*7680];
  if (wv < 15) {
    frag_write(FLb, flpk);
    frag_write(FRb, frpk);
  }
  __syncthreads();

  // ---- cost: p = tid>>1 (480 px), 2-way e-split, row-local clamp ----
  float* cvb = (float*)phis;            // 9*480*4 = 17,280 B <= 17,408
  if (tid < 960) {
    const int p  = tid >> 1;
    const int eh = tid & 1;
    const int row = (p >= NW) ? 1 : 0;
    const int w   = p - row*NW;
    float xf  = (float)w - d0v;
    float x0  = floorf(xf);
    float wfr = xf - x0;
    int jbl = (int)x0 - 4;

    unsigned fl[16];
    #pragma unroll
    for (int i = 0; i < 4; ++i) {
      int c4 = 4*eh + i;
      uint4 raw = *(const uint4*)&FLb[p*64 + ((c4 ^ swz(p))<<3)];
      fl[4*i+0]=raw.x; fl[4*i+1]=raw.y; fl[4*i+2]=raw.z; fl[4*i+3]=raw.w;
    }

    float D[10];
    #pragma unroll
    for (int t = 0; t < 10; ++t) {
      int j = jbl + t;
      j = j < 0 ? 0 : (j > NW-1 ? NW-1 : j);
      j += row*NW;
      float s = 0.f;
      #pragma unroll
      for (int i = 0; i < 4; ++i) {
        int c4 = 4*eh + i;
        uint4 raw = *(const uint4*)&FRb[j*64 + ((c4 ^ swz(j))<<3)];
        s = fdot2u(fl[4*i+0], raw.x, s);
        s = fdot2u(fl[4*i+1], raw.y, s);
        s = fdot2u(fl[4*i+2], raw.z, s);
        s = fdot2u(fl[4*i+3], raw.w, s);
      }
      D[t] = s;
    }
    #pragma unroll
    for (int t = 0; t < 10; ++t) D[t] += __shfl_xor(D[t], 1, 64);

    if (eh == 0) {
      #pragma unroll
      for (int k = 0; k < 5; ++k) {
        int t0 = 8 - k;
        cvb[k*P2 + p] = (1.f - wfr)*D[t0] + wfr*D[t0+1];
      }
    } else {
      #pragma unroll
      for (int k = 5; k < 9; ++k) {
        int t0 = 8 - k;
        cvb[k*P2 + p] = (1.f - wfr)*D[t0] + wfr*D[t0+1];
      }
    }
  }
  __syncthreads();

  // ---- out store: 1080 float4 (9 planes x 120), rows contiguous ----
  #pragma unroll
  for (int i = 0; i < 2; ++i) {
    int t = i*1024 + tid;
    if (t < 1080) {
      int k = t/120, w4 = t - 120*k;
      float4 v = *(const float4*)&cvb[k*P2 + 4*w4];
      *(float4*)(outg + (size_t)(b*NK + k)*PLANE + (size_t)hp*P2 + 4*w4) = v;
    }
  }
}

extern "C" void kernel_launch(void* const* d_in, const int* in_sizes, int n_in,
                              void* d_out, int out_size, void* d_ws, size_t ws_size,
                              hipStream_t stream) {
  const float* xL   = (const float*)d_in[0];
  const float* xR   = (const float*)d_in[1];
  const float* d0g  = (const float*)d_in[2];
  const float* phig = (const float*)d_in[3];
  float* outg = (float*)d_out;
  fused_kernel<<<dim3(NB*NH/2), dim3(1024), 0, stream>>>(xL, xR, d0g, phig, outg);
}

// Round 9
// 147.750 us; speedup vs baseline: 1.0401x; 1.0336x over previous
//
#include <hip/hip_runtime.h>
#include <hip/hip_bf16.h>

#define NB 4
#define NC 128
#define NH 128
#define NW 240
#define NE 64
#define NK 9
#define PLANE (NH*NW)        // 30720
#define CHW (NC*PLANE)
#define P2 480               // pixels per block (2 rows)

typedef __attribute__((ext_vector_type(8))) short short8;
typedef __attribute__((ext_vector_type(4))) short short4v;
typedef __attribute__((ext_vector_type(4))) float f32x4;
typedef __attribute__((ext_vector_type(2))) __fp16 fp16x2;
typedef __attribute__((ext_vector_type(4))) __fp16 fp16x4;

__device__ __forceinline__ unsigned pkh(float x, float y){
  fp16x2 h = __builtin_amdgcn_cvt_pkrtz(x, y);
  return __builtin_bit_cast(unsigned, h);
}
__device__ __forceinline__ float fdot2u(unsigned a, unsigned b, float c){
#if __has_builtin(__builtin_amdgcn_fdot2)
  return __builtin_amdgcn_fdot2(__builtin_bit_cast(fp16x2,a),
                                __builtin_bit_cast(fp16x2,b), c, false);
#else
  fp16x2 ha = __builtin_bit_cast(fp16x2,a), hb = __builtin_bit_cast(fp16x2,b);
  return c + (float)ha[0]*(float)hb[0] + (float)ha[1]*(float)hb[1];
#endif
}
__device__ __forceinline__ int swz(int r){ return (r ^ (r>>3)) & 7; }

__device__ __forceinline__ void gload_lds16(const float* g, float* lds_u, int lane){
#if __has_builtin(__builtin_amdgcn_global_load_lds)
  __builtin_amdgcn_global_load_lds(
      (const __attribute__((address_space(1))) unsigned*)g,
      (__attribute__((address_space(3))) unsigned*)lds_u, 16, 0, 0);
#else
  *(float4*)(lds_u + 4*lane) = *(const float4*)g;
#endif
}

#define WAITB(N) do {                                                        \
    asm volatile("s_waitcnt vmcnt(" #N ") lgkmcnt(0)" ::: "memory");         \
    __builtin_amdgcn_s_barrier();                                            \
    __builtin_amdgcn_sched_barrier(0);                                       \
  } while (0)

// ======================================================================
// R8 structure (verified), work-slimmed: native-K 16x16x16f16 MFMA
// (no zero padding), GEMM balanced over all 16 waves (30 n-tiles).
// 256 blocks x 1024 thr, chunk = 16ch x 480px fp32 (contig 1920-B segs),
// 4 bufs, 3-deep counted-vmcnt pipeline. LDS 140,288 B.
// ======================================================================
__global__ __launch_bounds__(1024, 4)
void fused_kernel(const float* __restrict__ xL,
                  const float* __restrict__ xR,
                  const float* __restrict__ d0g,
                  const float* __restrict__ phig,
                  float* __restrict__ outg)
{
  __shared__ __attribute__((aligned(16))) float bufs[4*7680];           // 122,880 B
  __shared__ __attribute__((aligned(16))) unsigned short phis[NE*136];  // 17,408 B

  const int tid  = threadIdx.x;
  const int lane = tid & 63;
  const int wv   = tid >> 6;
  const int b    = blockIdx.x >> 6;    // 256 blocks: b, h-pair
  const int hp   = blockIdx.x & 63;
  const size_t base = (size_t)b*CHW + (size_t)hp*P2;   // x[b][0][2hp][0]
  const int pixbase = b*PLANE + hp*P2;                  // d0/out pixel base

  const int mrow = lane & 15;
  const int kg   = lane >> 4;

  // chunk q in [0,16): side q>>3, kq=q&7 -> 16 channels, buf q&3.
  auto issue_chunk = [&](int q){
    const float* src = (q < 8) ? xL : xR;
    const int kq = q & 7;
    float* buf = &bufs[(q & 3)*7680];
    #pragma unroll
    for (int i = 0; i < 2; ++i) {
      int qq = 2*wv + i;
      if (qq < 30) {
        int g4 = qq*64 + lane;
        int c = g4/120, s4 = g4 - 120*c;     // [16 ch][120 f4]
        gload_lds16(src + base + (size_t)(16*kq + c)*PLANE + 4*s4,
                    buf + qq*256, lane);
      }
    }
  };

  // one K=16 slice over 480 px; wave w owns n-tiles {w} and {16+w | w<14}
  auto gemm_round = [&](int q, f32x4 (&acc)[2][4]){
    const int kq = q & 7;
    const float* bf = &bufs[(q & 3)*7680];
    fp16x4 af[4];
    #pragma unroll
    for (int mt = 0; mt < 4; ++mt)
      af[mt] = __builtin_bit_cast(fp16x4,
          *(const short4v*)&phis[(16*mt + mrow)*136 + 16*kq + 4*kg]);
    #pragma unroll
    for (int tt = 0; tt < 2; ++tt) {
      if (tt == 0 || wv < 14) {
        const int n = 16*(wv + 16*tt) + mrow;
        fp16x4 bv;
        #pragma unroll
        for (int j = 0; j < 4; ++j)
          bv[j] = (__fp16)bf[(4*kg + j)*P2 + n];
        #pragma unroll
        for (int mt = 0; mt < 4; ++mt)
          acc[tt][mt] = __builtin_amdgcn_mfma_f32_16x16x16f16(af[mt], bv, acc[tt][mt], 0, 0, 0);
      }
    }
  };

  auto norm_pack = [&](f32x4 (&acc)[2][4], uint2 (&pk)[2][4]){
    #pragma unroll
    for (int tt = 0; tt < 2; ++tt) {
      if (tt == 0 || wv < 14) {
        float ss = 0.f;
        #pragma unroll
        for (int mt = 0; mt < 4; ++mt)
          #pragma unroll
          for (int r = 0; r < 4; ++r)
            ss += acc[tt][mt][r]*acc[tt][mt][r];
        ss += __shfl_xor(ss, 16, 64);
        ss += __shfl_xor(ss, 32, 64);
        float inv = 1.f/(sqrtf(ss) + 1e-6f);
        #pragma unroll
        for (int mt = 0; mt < 4; ++mt) {
          pk[tt][mt].x = pkh(acc[tt][mt][0]*inv, acc[tt][mt][1]*inv);
          pk[tt][mt].y = pkh(acc[tt][mt][2]*inv, acc[tt][mt][3]*inv);
        }
      }
    }
  };

  auto frag_write = [&](unsigned short* dst, uint2 (&pk)[2][4]){
    #pragma unroll
    for (int tt = 0; tt < 2; ++tt) {
      if (tt == 0 || wv < 14) {
        const int n = 16*(wv + 16*tt) + mrow;
        #pragma unroll
        for (int mt = 0; mt < 4; ++mt) {
          int e0 = 16*mt + 4*kg;
          int pos = n*64 + (((e0>>3) ^ swz(n))<<3) + (e0&7);
          *(uint2*)&dst[pos] = pk[tt][mt];
        }
      }
    }
  };

  // ---- prologue: d0 + phi, then chunks 0..2 ----
  float d0v = (tid < 960) ? d0g[pixbase + (tid >> 1)] : 0.f;
  float4 pr[2];
  #pragma unroll
  for (int i = 0; i < 2; ++i) {
    int idx = i*1024 + tid;
    pr[i] = *(const float4*)(phig + (idx>>5)*128 + 4*(idx&31));
  }
  #pragma unroll
  for (int i = 0; i < 2; ++i) {
    int idx = i*1024 + tid;
    uint2 pk; pk.x = pkh(pr[i].x, pr[i].y); pk.y = pkh(pr[i].z, pr[i].w);
    *(uint2*)&phis[(idx>>5)*136 + 4*(idx&31)] = pk;
  }
  issue_chunk(0); issue_chunk(1); issue_chunk(2);

  f32x4 accL[2][4], accR[2][4];
  #pragma unroll
  for (int tt = 0; tt < 2; ++tt)
    #pragma unroll
    for (int mt = 0; mt < 4; ++mt) {
      accL[tt][mt] = (f32x4){0.f,0.f,0.f,0.f};
      accR[tt][mt] = (f32x4){0.f,0.f,0.f,0.f};
    }
  uint2 flpk[2][4], frpk[2][4];

  // ---- 16 rounds, 3-deep counted-vmcnt ----
  WAITB(4); issue_chunk(3);  gemm_round(0,  accL);
  WAITB(4); issue_chunk(4);  gemm_round(1,  accL);
  WAITB(4); issue_chunk(5);  gemm_round(2,  accL);
  WAITB(4); issue_chunk(6);  gemm_round(3,  accL);
  WAITB(4); issue_chunk(7);  gemm_round(4,  accL);
  WAITB(4); issue_chunk(8);  gemm_round(5,  accL);
  WAITB(4); issue_chunk(9);  gemm_round(6,  accL);
  WAITB(4); issue_chunk(10); gemm_round(7,  accL);
  norm_pack(accL, flpk);
  WAITB(4); issue_chunk(11); gemm_round(8,  accR);
  WAITB(4); issue_chunk(12); gemm_round(9,  accR);
  WAITB(4); issue_chunk(13); gemm_round(10, accR);
  WAITB(4); issue_chunk(14); gemm_round(11, accR);
  WAITB(4); issue_chunk(15); gemm_round(12, accR);
  WAITB(4);                  gemm_round(13, accR);
  WAITB(2);                  gemm_round(14, accR);
  WAITB(0);                  gemm_round(15, accR);
  norm_pack(accR, frpk);

  // ---- epilogue: all buf reads done -> overwrite with FL/FR frags ----
  asm volatile("s_waitcnt lgkmcnt(0)" ::: "memory");
  __builtin_amdgcn_s_barrier();
  __builtin_amdgcn_sched_barrier(0);
  unsigned short* FLb = (unsigned short*)&bufs[0];        // 480x64 fp16
  unsigned short* FRb = (unsigned short*)&bufs[2*7680];
  frag_write(FLb, flpk);
  frag_write(FRb, frpk);
  __syncthreads();

  // ---- cost: p = tid>>1 (480 px), 2-way e-split, row-local clamp ----
  float* cvb = (float*)phis;            // 9*480*4 = 17,280 B <= 17,408
  if (tid < 960) {
    const int p  = tid >> 1;
    const int eh = tid & 1;
    const int row = (p >= NW) ? 1 : 0;
    const int w   = p - row*NW;
    float xf  = (float)w - d0v;
    float x0  = floorf(xf);
    float wfr = xf - x0;
    int jbl = (int)x0 - 4;

    unsigned fl[16];
    #pragma unroll
    for (int i = 0; i < 4; ++i) {
      int c4 = 4*eh + i;
      uint4 raw = *(const uint4*)&FLb[p*64 + ((c4 ^ swz(p))<<3)];
      fl[4*i+0]=raw.x; fl[4*i+1]=raw.y; fl[4*i+2]=raw.z; fl[4*i+3]=raw.w;
    }

    float D[10];
    #pragma unroll
    for (int t = 0; t < 10; ++t) {
      int j = jbl + t;
      j = j < 0 ? 0 : (j > NW-1 ? NW-1 : j);
      j += row*NW;
      float s = 0.f;
      #pragma unroll
      for (int i = 0; i < 4; ++i) {
        int c4 = 4*eh + i;
        uint4 raw = *(const uint4*)&FRb[j*64 + ((c4 ^ swz(j))<<3)];
        s = fdot2u(fl[4*i+0], raw.x, s);
        s = fdot2u(fl[4*i+1], raw.y, s);
        s = fdot2u(fl[4*i+2], raw.z, s);
        s = fdot2u(fl[4*i+3], raw.w, s);
      }
      D[t] = s;
    }
    #pragma unroll
    for (int t = 0; t < 10; ++t) D[t] += __shfl_xor(D[t], 1, 64);

    if (eh == 0) {
      #pragma unroll
      for (int k = 0; k < 5; ++k) {
        int t0 = 8 - k;
        cvb[k*P2 + p] = (1.f - wfr)*D[t0] + wfr*D[t0+1];
      }
    } else {
      #pragma unroll
      for (int k = 5; k < 9; ++k) {
        int t0 = 8 - k;
        cvb[k*P2 + p] = (1.f - wfr)*D[t0] + wfr*D[t0+1];
      }
    }
  }
  __syncthreads();

  // ---- out store: 1080 float4 (9 planes x 120), rows contiguous ----
  #pragma unroll
  for (int i = 0; i < 2; ++i) {
    int t = i*1024 + tid;
    if (t < 1080) {
      int k = t/120, w4 = t - 120*k;
      float4 v = *(const float4*)&cvb[k*P2 + 4*w4];
      *(float4*)(outg + (size_t)(b*NK + k)*PLANE + (size_t)hp*P2 + 4*w4) = v;
    }
  }
}

extern "C" void kernel_launch(void* const* d_in, const int* in_sizes, int n_in,
                              void* d_out, int out_size, void* d_ws, size_t ws_size,
                              hipStream_t stream) {
  const float* xL   = (const float*)d_in[0];
  const float* xR   = (const float*)d_in[1];
  const float* d0g  = (const float*)d_in[2];
  const float* phig = (const float*)d_in[3];
  float* outg = (float*)d_out;
  fused_kernel<<<dim3(NB*NH/2), dim3(1024), 0, stream>>>(xL, xR, d0g, phig, outg);
}